// Round 8
// baseline (81.666 us; speedup 1.0000x reference)
//
#include <hip/hip_runtime.h>
#include <hip/hip_bf16.h>
#include <math.h>

// Conditional_Embedding_Contrastive_loss on MI355X (gfx950)
// N=4096, D=1024, C=1000. Output: scalar f32 loss.
// R5: symmetric Gram (upper-tri tiles only, mirrored epilogue) + bit-packed cls_mask.

#define NN   4096
#define DD   1024
#define NCLS 1000
#define EPSF 1e-8f
#define MW   (NN / 32)   // 128 mask words per class row

typedef short bf16x8 __attribute__((ext_vector_type(8)));
typedef float f32x4  __attribute__((ext_vector_type(4)));

// ---------- kernel 0: detect labels dtype (int32 vs int64) and compact ----------
__global__ void k_labels(const int* __restrict__ lraw, int* __restrict__ lab) {
  __shared__ int stride_s;
  if (threadIdx.x == 0) {
    int stride = 2;  // assume int64 (little-endian)
    #pragma unroll
    for (int t = 0; t < 8; ++t) {
      int lo = lraw[2 * t], hi = lraw[2 * t + 1];
      if (hi != 0 || (unsigned)lo >= (unsigned)NCLS) { stride = 1; break; }
    }
    stride_s = stride;
  }
  __syncthreads();
  const int s = stride_s;
  for (int i = threadIdx.x; i < NN; i += blockDim.x) lab[i] = lraw[i * s];
}

// ---------- kernel 0b: bit-pack cls_mask [C][N] ints -> [C][N/32] u32 ----------
__global__ __launch_bounds__(256) void k_packmask(const int* __restrict__ cmask,
                                                  unsigned int* __restrict__ mbits) {
  const int wword = blockIdx.x * 256 + threadIdx.x;     // 0 .. C*MW-1
  const int* src = cmask + (size_t)wword * 32;
  unsigned int v = 0;
  #pragma unroll
  for (int q = 0; q < 8; ++q) {
    const int4 c = *(const int4*)(src + q * 4);
    v |= (c.x != 0 ? 1u : 0u) << (q * 4 + 0);
    v |= (c.y != 0 ? 1u : 0u) << (q * 4 + 1);
    v |= (c.z != 0 ? 1u : 0u) << (q * 4 + 2);
    v |= (c.w != 0 ? 1u : 0u) << (q * 4 + 3);
  }
  mbits[wword] = v;
}

// ---------- kernel 1: per-row norms, inst2embed_pos, f32->bf16 pack, zero-init ----------
__global__ __launch_bounds__(256) void k_rowstats(
    const float* __restrict__ X, const float* __restrict__ A,
    const float* __restrict__ Tp, ushort* __restrict__ Xb,
    float* __restrict__ rnx, float* __restrict__ rnT,
    float* __restrict__ epos,
    float* __restrict__ sfull, float* __restrict__ smask,
    float* __restrict__ out) {
  const int i = blockIdx.x;
  const int t = threadIdx.x;
  const size_t base = (size_t)i * DD + t * 4;
  const float4 xv = *(const float4*)(X + base);
  const float4 av = *(const float4*)(A + base);
  float sxx = xv.x * xv.x + xv.y * xv.y + xv.z * xv.z + xv.w * xv.w;
  float saa = av.x * av.x + av.y * av.y + av.z * av.z + av.w * av.w;
  float sxa = xv.x * av.x + xv.y * av.y + xv.z * av.z + xv.w * av.w;

  ushort4 pk;
  { __hip_bfloat16 b;
    b = __float2bfloat16(xv.x); pk.x = *(const ushort*)&b;
    b = __float2bfloat16(xv.y); pk.y = *(const ushort*)&b;
    b = __float2bfloat16(xv.z); pk.z = *(const ushort*)&b;
    b = __float2bfloat16(xv.w); pk.w = *(const ushort*)&b; }
  *(ushort4*)(Xb + base) = pk;

  #pragma unroll
  for (int off = 32; off > 0; off >>= 1) {
    sxx += __shfl_down(sxx, off);
    saa += __shfl_down(saa, off);
    sxa += __shfl_down(sxa, off);
  }
  __shared__ float red[3][4];
  const int w = t >> 6;
  if ((t & 63) == 0) { red[0][w] = sxx; red[1][w] = saa; red[2][w] = sxa; }
  __syncthreads();
  if (t == 0) {
    const float a  = red[0][0] + red[0][1] + red[0][2] + red[0][3];
    const float bb = red[1][0] + red[1][1] + red[1][2] + red[1][3];
    const float c  = red[2][0] + red[2][1] + red[2][2] + red[2][3];
    const float nxi = sqrtf(a), nai = sqrtf(bb);
    const float rT  = 1.0f / Tp[0];
    const float r   = 1.0f / fmaxf(nxi, 1e-20f);
    rnx[i] = r;
    rnT[i] = r * rT;
    epos[i] = expf((c / fmaxf(nxi * nai, EPSF)) * rT);
    sfull[i] = 0.f;
    smask[i] = 0.f;
    if (i == 0) out[0] = 0.f;
  }
}

// ---------- kernel 2: symmetric fused Gram (128x128 tiles, upper triangle) ----------
#define BM 128
#define BK 64
// LDS: row-major [128][64] bf16, 8x16B slots/row, XOR swizzle phys=log^(row&7),
// pre-swizzled on the GLOBAL source since global_load_lds writes linearly.

__global__ __launch_bounds__(256) void k_gram(
    const ushort* __restrict__ Xb, const float* __restrict__ rnx,
    const float* __restrict__ rnT,
    const int* __restrict__ lab, const unsigned int* __restrict__ mbits,
    float* __restrict__ sfull, float* __restrict__ smask) {
  __shared__ __align__(16) char As[BM * BK * 2];   // 16 KB
  __shared__ __align__(16) char Bs[BM * BK * 2];   // 16 KB
  const int tid  = threadIdx.x;
  const int lane = tid & 63;
  const int w    = tid >> 6;
  const int wr   = w >> 1, wc = w & 1;

  // triangular decode: tile t -> (by, bx), bx >= by
  const int t = blockIdx.x;
  int a = (int)((sqrtf(8.f * (float)t + 1.f) - 1.f) * 0.5f);
  while ((a + 1) * (a + 2) / 2 <= t) ++a;
  while (a * (a + 1) / 2 > t) --a;
  const int by = t - a * (a + 1) / 2;
  const int bx = a;
  const bool offdiag = (bx != by);
  const int i0 = by * BM;
  const int j0 = bx * BM;

  const int sslot = (lane & 7) ^ (lane >> 3);  // pre-swizzled global k-slot

  f32x4 acc[4][4];
  #pragma unroll
  for (int m = 0; m < 4; ++m)
    #pragma unroll
    for (int n = 0; n < 4; ++n)
      acc[m][n] = (f32x4){0.f, 0.f, 0.f, 0.f};

  const ushort* pA[4];
  const ushort* pB[4];
  #pragma unroll
  for (int q = 0; q < 4; ++q) {
    const int row = q * 32 + w * 8 + (lane >> 3);
    pA[q] = Xb + (size_t)(i0 + row) * DD + sslot * 8;
    pB[q] = Xb + (size_t)(j0 + row) * DD + sslot * 8;
  }

  for (int k0 = 0; k0 < DD; k0 += BK) {
    #pragma unroll
    for (int q = 0; q < 4; ++q) {
      __builtin_amdgcn_global_load_lds(
          (const __attribute__((address_space(1))) void*)(pA[q] + k0),
          (__attribute__((address_space(3))) void*)(As + (q * 4 + w) * 1024), 16, 0, 0);
      __builtin_amdgcn_global_load_lds(
          (const __attribute__((address_space(1))) void*)(pB[q] + k0),
          (__attribute__((address_space(3))) void*)(Bs + (q * 4 + w) * 1024), 16, 0, 0);
    }
    __syncthreads();

    #pragma unroll
    for (int ks = 0; ks < 2; ++ks) {
      const int slot = ((ks << 2) + (lane >> 4)) ^ (lane & 7);
      bf16x8 af[4], bfr[4];
      #pragma unroll
      for (int m = 0; m < 4; ++m) {
        const int r = (wr << 6) + (m << 4) + (lane & 15);
        af[m] = *(const bf16x8*)(As + r * 128 + (slot << 4));
      }
      #pragma unroll
      for (int n = 0; n < 4; ++n) {
        const int r = (wc << 6) + (n << 4) + (lane & 15);
        bfr[n] = *(const bf16x8*)(Bs + r * 128 + (slot << 4));
      }
      #pragma unroll
      for (int m = 0; m < 4; ++m)
        #pragma unroll
        for (int n = 0; n < 4; ++n)
          acc[m][n] = __builtin_amdgcn_mfma_f32_16x16x32_bf16(af[m], bfr[n], acc[m][n], 0, 0, 0);
    }
    __syncthreads();
  }

  // ---- epilogue. C/D map: col=lane&15, row=(lane>>4)*4+reg.
  // i-side: rows i of this tile (sum over tile cols j).
  // j-side (offdiag only): mirror contributions to rows j (sum over tile rows i).
  float rnT_j[4];
  unsigned long long wj[4];           // mask bits row lab[j_n], i-span of this wave
  #pragma unroll
  for (int n = 0; n < 4; ++n) {
    const int j = j0 + (wc << 6) + (n << 4) + (lane & 15);
    rnT_j[n] = rnT[j];
    wj[n] = *(const unsigned long long*)(mbits + (size_t)lab[j] * MW + (i0 >> 5) + (wr << 1));
  }
  float pse[4] = {0.f, 0.f, 0.f, 0.f}, psm[4] = {0.f, 0.f, 0.f, 0.f};

  #pragma unroll
  for (int m = 0; m < 4; ++m) {
    #pragma unroll
    for (int r = 0; r < 4; ++r) {
      const int irow = (m << 4) + ((lane >> 4) << 2) + r;      // local row in wave's 64-span (global: wr<<6 + irow)
      const int i = i0 + (wr << 6) + irow;
      const float rni = rnx[i];
      const unsigned long long wi =
          *(const unsigned long long*)(mbits + (size_t)lab[i] * MW + (j0 >> 5) + (wc << 1));
      float se = 0.f, sm = 0.f;
      #pragma unroll
      for (int n = 0; n < 4; ++n) {
        const int j = j0 + (wc << 6) + (n << 4) + (lane & 15);
        float e = __expf(acc[m][n][r] * rni * rnT_j[n]);
        if (i == j) e = 0.f;                                   // remove_diag
        se += e;
        const int bposj = (n << 4) + (lane & 15);              // j within wave's col-span
        sm += ((wi >> bposj) & 1ull) ? e : 0.f;
        pse[n] += e;
        psm[n] += ((wj[n] >> irow) & 1ull) ? e : 0.f;
      }
      #pragma unroll
      for (int off = 1; off < 16; off <<= 1) {
        se += __shfl_xor(se, off);
        sm += __shfl_xor(sm, off);
      }
      if ((lane & 15) == 0) {
        atomicAdd(&sfull[i], se);
        atomicAdd(&smask[i], sm);
      }
    }
  }

  if (offdiag) {
    #pragma unroll
    for (int n = 0; n < 4; ++n) {
      float se = pse[n], sm = psm[n];
      se += __shfl_xor(se, 16); se += __shfl_xor(se, 32);
      sm += __shfl_xor(sm, 16); sm += __shfl_xor(sm, 32);
      if ((lane >> 4) == 0) {
        const int j = j0 + (wc << 6) + (n << 4) + lane;
        atomicAdd(&sfull[j], se);
        atomicAdd(&smask[j], sm);
      }
    }
  }
}

// ---------- kernel 3: loss = mean(log(den) - log(num)) ----------
__global__ __launch_bounds__(256) void k_final(
    const float* __restrict__ sfull, const float* __restrict__ smask,
    const float* __restrict__ epos, float* __restrict__ out) {
  const int idx = blockIdx.x * 256 + threadIdx.x;
  const float ep  = epos[idx];
  const float num = smask[idx] + ep;
  const float den = ep + sfull[idx];
  float v = (logf(den) - logf(num)) * (1.0f / (float)NN);
  #pragma unroll
  for (int off = 32; off > 0; off >>= 1) v += __shfl_down(v, off);
  __shared__ float red[4];
  if ((threadIdx.x & 63) == 0) red[threadIdx.x >> 6] = v;
  __syncthreads();
  if (threadIdx.x == 0) atomicAdd(out, red[0] + red[1] + red[2] + red[3]);
}

extern "C" void kernel_launch(void* const* d_in, const int* in_sizes, int n_in,
                              void* d_out, int out_size, void* d_ws, size_t ws_size,
                              hipStream_t stream) {
  const float* X     = (const float*)d_in[0];
  const float* A     = (const float*)d_in[1];
  const int*   cmask = (const int*)d_in[2];
  const int*   lraw  = (const int*)d_in[3];
  const float* Tp    = (const float*)d_in[4];
  float* out = (float*)d_out;

  char* ws = (char*)d_ws;
  ushort* Xb   = (ushort*)ws;                          // 8 MB
  float* rnx   = (float*)(ws + (size_t)NN * DD * 2);
  float* rnT   = rnx + NN;
  float* epos  = rnT + NN;
  float* sfull = epos + NN;
  float* smask = sfull + NN;
  int*   lab   = (int*)(smask + NN);
  unsigned int* mbits = (unsigned int*)(lab + NN);     // 512 KB, 8B-aligned

  const int NTILE = (NN / BM) * (NN / BM + 1) / 2;     // 528

  hipLaunchKernelGGL(k_labels,   dim3(1),               dim3(256), 0, stream, lraw, lab);
  hipLaunchKernelGGL(k_packmask, dim3(NCLS * MW / 256), dim3(256), 0, stream, cmask, mbits);
  hipLaunchKernelGGL(k_rowstats, dim3(NN),              dim3(256), 0, stream, X, A, Tp, Xb, rnx, rnT, epos, sfull, smask, out);
  hipLaunchKernelGGL(k_gram,     dim3(NTILE),           dim3(256), 0, stream, Xb, rnx, rnT, lab, mbits, sfull, smask);
  hipLaunchKernelGGL(k_final,    dim3(NN/256),          dim3(256), 0, stream, sfull, smask, epos, out);
}